// Round 13
// baseline (485.591 us; speedup 1.0000x reference)
//
#include <hip/hip_runtime.h>
#include <math.h>

// RNN_197568496340: 6-layer ReLU RNN (T=1024,B=2048,IN=2,H=20) + FC(20->2) + log_softmax.
//
// R18: 2 batch elements per wave (1024 blocks), R11 lag-1 schedule, masked fences.
// Rationale (R13/R17 profiling): 2 symmetric waves/SIMD convoy-stall together; ~40%
// idle is structural. One wave with TWO interleaved recurrences gets:
//  - in-wave ILP: batch B's 80 MACs cover batch A's LDS turnaround (and vice versa);
//  - weight registers SHARED across the pair (80 floats serve 160 MACs/step);
//  - full 256-VGPR budget at 1 wave/SIMD (waves_per_eu(1,1)) -> no AGPR parking;
//  - float4 fusion: x load + head store cover both batches in one op.
// Kept (validated): masked sched_barrier(0x77) in steady (R17: DS order preserved,
// ALU/VMEM may cross), full fence on edges; deferred log_softmax; steady/edge split;
// XCD swizzle; fp32 only (R15: fp16/bf16 die numerically, error x1e6).

#define TT 1024
#define BB 2048
#define HH 20
#define LL 6
#define SLOTW 40
#define BUFW  (8 * SLOTW)       // 320 words/parity/batch: slots 0=x,1..6=h,7=zeros
#define XS 0
#define NB4 1024                // row stride in float4 units (2048*2/4)

// ws layout (floats)
#define WS_WI   0               // padded Wih: [6][20][20] (layer0 = Wih0 zero-padded)
#define WS_BIAS 2400            // BiasTab: [61][2]  (role 60 = fcb)

typedef float f4 __attribute__((ext_vector_type(4)));

__global__ void stage_ws(const float* __restrict__ Wih0,
                         const float* __restrict__ Wih,
                         const float* __restrict__ bih,
                         const float* __restrict__ bhh,
                         const float* __restrict__ fcb,
                         float* __restrict__ ws) {
    const int i = threadIdx.x + blockIdx.x * blockDim.x;
    if (i < 2400) {
        const int l = i / 400, r = i % 400, j = r / 20, k = r % 20;
        float v;
        if (l == 0) v = (k < 2) ? Wih0[j * 2 + k] : 0.f;
        else        v = Wih[(l - 1) * 400 + r];
        ws[WS_WI + i] = v;
    }
    if (i < 122) {
        const int role = i >> 1, c = i & 1;
        float v;
        if (role < 60) {
            const int l = role / 10, j = 2 * (role % 10) + c;
            v = bih[l * HH + j] + bhh[l * HH + j];
        } else {
            v = fcb[c];
        }
        ws[WS_BIAS + i] = v;
    }
}

__global__ void logsm(float* __restrict__ o) {
    const size_t n = (size_t)TT * BB;            // float2 elements
    float2* p = (float2*)o;
    for (size_t idx = (size_t)blockIdx.x * blockDim.x + threadIdx.x; idx < n;
         idx += (size_t)gridDim.x * blockDim.x) {
        float2 v = p[idx];
        const float mx  = fmaxf(v.x, v.y);
        const float lse = mx + __logf(__expf(v.x - mx) + __expf(v.y - mx));
        p[idx] = make_float2(v.x - lse, v.y - lse);
    }
}

// ---- hot-loop macros ----

#define MAC4(acc, W, Q) do {                                       \
    acc = fmaf((W).x, (Q).x, acc); acc = fmaf((W).y, (Q).y, acc);  \
    acc = fmaf((W).z, (Q).z, acc); acc = fmaf((W).w, (Q).w, acc); } while (0)

// one batch's 80 MACs (4 chains), weights shared
#define MACS(P0,P1,Q0,Q1, H0,H1,H2,H3,H4, I0,I1,I2,I3,I4)          \
    MAC4(P0,whA0,H0); MAC4(P1,whB0,H0); MAC4(Q0,wiA0,I0); MAC4(Q1,wiB0,I0); \
    MAC4(P0,whA1,H1); MAC4(P1,whB1,H1); MAC4(Q0,wiA1,I1); MAC4(Q1,wiB1,I1); \
    MAC4(P0,whA2,H2); MAC4(P1,whB2,H2); MAC4(Q0,wiA2,I2); MAC4(Q1,wiB2,I2); \
    MAC4(P0,whA3,H3); MAC4(P1,whB3,H3); MAC4(Q0,wiA3,I3); MAC4(Q1,wiB3,I3); \
    MAC4(P0,whA4,H4); MAC4(P1,whB4,H4); MAC4(Q0,wiA4,I4); MAC4(Q1,wiB4,I4)

// STEP(s, ph, rb, wb, steady, fullfence): dual-batch lag-1 micro-step
#define STEP(S_, PH_, RB_, WB_, ST_, FF_) do {                                     \
    const float* rb0_ = (RB_);              float* wb0_ = (WB_);                   \
    const float* rb1_ = rb0_ + 2 * BUFW;    float* wb1_ = wb0_ + 2 * BUFW;         \
    const f4* hp0_ = (const f4*)(rb0_ + hoff); const f4* ip0_ = (const f4*)(rb0_ + ioff); \
    const f4* hp1_ = (const f4*)(rb1_ + hoff); const f4* ip1_ = (const f4*)(rb1_ + ioff); \
    const f4 h00=hp0_[0],h01=hp0_[1],h02=hp0_[2],h03=hp0_[3],h04=hp0_[4];          \
    const f4 i00=ip0_[0],i01=ip0_[1],i02=ip0_[2],i03=ip0_[3],i04=ip0_[4];          \
    const f4 h10=hp1_[0],h11=hp1_[1],h12=hp1_[2],h13=hp1_[3],h14=hp1_[4];          \
    const f4 i10=ip1_[0],i11=ip1_[1],i12=ip1_[2],i13=ip1_[3],i14=ip1_[4];          \
    float p0=0.f,p1=0.f,q0=bt.x,q1=bt.y;                                           \
    float r0=0.f,r1=0.f,s0=bt.x,s1=bt.y;                                           \
    MACS(p0,p1,q0,q1, h00,h01,h02,h03,h04, i00,i01,i02,i03,i04);                   \
    MACS(r0,r1,s0,s1, h10,h11,h12,h13,h14, i10,i11,i12,i13,i14);                   \
    const float a00 = p0 + q0, a01 = p1 + q1;                                      \
    const float a10 = r0 + s0, a11 = r1 + s1;                                      \
    if (lane < 60) {                                                               \
        if ((ST_) || (unsigned)((S_) - l) < TT) {                                  \
            *(float2*)(wb0_ + hoff + j) = make_float2(fmaxf(a00,0.f), fmaxf(a01,0.f)); \
            *(float2*)(wb1_ + hoff + j) = make_float2(fmaxf(a10,0.f), fmaxf(a11,0.f)); \
        }                                                                          \
    } else if (lane == 60) {                                                       \
        if ((ST_) || (S_) >= LL) { f4 o_; o_.x=a00; o_.y=a01; o_.z=a10; o_.w=a11;  \
                                   *oph4 = o_; }                                   \
        oph4 += NB4;                                                               \
    } else {                                                                       \
        if (rdc == (PH_)) {                                                        \
            if ((ST_) || (S_) + 1 < TT) {                                          \
                *(float2*)(wb0_ + XS) = make_float2(xh.x, xh.y);                   \
                *(float2*)(wb1_ + XS) = make_float2(xh.z, xh.w);                   \
            }                                                                      \
            if ((ST_)) xh = *xq4; else if (xq4 <= xend4) xh = *xq4;                \
            xq4 += 3 * (size_t)NB4;                                                \
        }                                                                          \
    }                                                                              \
    if (FF_) __builtin_amdgcn_sched_barrier(0);                                    \
    else     __builtin_amdgcn_sched_barrier(0x77);  /* DS pinned, ALU/VMEM free */ \
} while (0)

__global__ __attribute__((amdgpu_flat_work_group_size(64, 64), amdgpu_waves_per_eu(1, 1)))
void rnn_fused(const float* __restrict__ x,      // [1024][2048][2]
               const float* __restrict__ Whh,    // [6][20][20]
               const float* __restrict__ fcw,    // [2][20]
               const float* __restrict__ ws,     // staged WI_pad + BiasTab
               float* __restrict__ out)          // [1024][2048][2] (raw logits here)
{
    __shared__ __align__(16) float As[4 * BUFW];   // 5120 B: batch0 A/B, batch1 A/B

    const int lane = threadIdx.x;
    // XCD swizzle on the 1024 pair-blocks; pair bq covers batches {2bq, 2bq+1}
    const int bq = ((blockIdx.x & 7) << 7) | (blockIdx.x >> 3);

    const int  role = (lane < 60) ? lane : 60;
    const int  l    = role / 10;            // 0..6 (6 = head pseudo-layer)
    const int  j    = 2 * (role % 10);      // 0 for head
    const bool head = (role == 60);

    // ---- branch-free uniform weight init (shared across the batch pair) ----
    const f4* pwh = (const f4*)(head ? Whh : (Whh + (l * HH + j) * HH));
    const f4* pwi = (const f4*)(head ? fcw : (ws + WS_WI + (l * HH + j) * HH));
    const float2 bt = *(const float2*)(ws + WS_BIAS + 2 * role);

    f4 whA0 = pwh[0], whA1 = pwh[1], whA2 = pwh[2], whA3 = pwh[3], whA4 = pwh[4];
    f4 whB0 = pwh[5], whB1 = pwh[6], whB2 = pwh[7], whB3 = pwh[8], whB4 = pwh[9];
    f4 wiA0 = pwi[0], wiA1 = pwi[1], wiA2 = pwi[2], wiA3 = pwi[3], wiA4 = pwi[4];
    f4 wiB0 = pwi[5], wiB1 = pwi[6], wiB2 = pwi[7], wiB3 = pwi[8], wiB4 = pwi[9];

    // per-lane LDS word offsets (uniform formula, head included)
    const int ioff = l * SLOTW;             // input slot (head: slot 6 = h5)
    const int hoff = (l + 1) * SLOTW;       // recurrent slot (head: slot 7 = zeros)

    float* const bufA = As;                 // batch0 parity A (batch1 at +2*BUFW)
    float* const bufB = As + BUFW;          // batch0 parity B

    // ---- LDS init: everything zero ----
    for (int i = lane; i < 4 * BUFW; i += 64) As[i] = 0.f;

    // x staging: float4 covers both batches. x[t][2bq..2bq+1][0..1] = xp4[t*NB4+bq]
    const f4* xp4 = (const f4*)x;
    f4 xh; xh.x = 0.f; xh.y = 0.f; xh.z = 0.f; xh.w = 0.f;
    if (lane == 61) { const f4 v = xp4[bq];
                      *(float2*)(bufA + XS)            = make_float2(v.x, v.y);
                      *(float2*)(bufA + 2*BUFW + XS)   = make_float2(v.z, v.w); }
    if (lane >= 61) xh = xp4[(size_t)(lane - 60) * NB4 + bq];      // hold x(1..3)

    const int rdc = (lane >= 61) ? (lane - 61) : 0;                // ring phase 0..2
    const f4* xq4   = xp4 + (size_t)(rdc + 4) * NB4 + bq;          // prefetch x[s+4]
    const f4* xend4 = xp4 + (size_t)(TT - 1) * NB4 + bq;
    f4* oph4 = (f4*)out + bq - (ptrdiff_t)LL * NB4;                // head t = s-6

    // ---- edge pre: s = 0..5 (full fences; ph = s%3; buffers alternate) ----
    STEP(0, 0, bufA, bufB, 0, 1); STEP(1, 1, bufB, bufA, 0, 1);
    STEP(2, 2, bufA, bufB, 0, 1); STEP(3, 0, bufB, bufA, 0, 1);
    STEP(4, 1, bufA, bufB, 0, 1); STEP(5, 2, bufB, bufA, 0, 1);

    // ---- steady: s in [6,1020), 169 x 6 steps, guards folded, masked fences ----
#pragma unroll 1
    for (int it = 0; it < 169; ++it) {
        STEP(0, 0, bufA, bufB, 1, 0); STEP(0, 1, bufB, bufA, 1, 0);
        STEP(0, 2, bufA, bufB, 1, 0); STEP(0, 0, bufB, bufA, 1, 0);
        STEP(0, 1, bufA, bufB, 1, 0); STEP(0, 2, bufB, bufA, 1, 0);
    }

    // ---- edge post: s = 1020..1029 (full fences; 1020%3 == 0) ----
    STEP(1020, 0, bufA, bufB, 0, 1); STEP(1021, 1, bufB, bufA, 0, 1);
    STEP(1022, 2, bufA, bufB, 0, 1); STEP(1023, 0, bufB, bufA, 0, 1);
    STEP(1024, 1, bufA, bufB, 0, 1); STEP(1025, 2, bufB, bufA, 0, 1);
    STEP(1026, 0, bufA, bufB, 0, 1); STEP(1027, 1, bufB, bufA, 0, 1);
    STEP(1028, 2, bufA, bufB, 0, 1); STEP(1029, 0, bufB, bufA, 0, 1);
}

extern "C" void kernel_launch(void* const* d_in, const int* in_sizes, int n_in,
                              void* d_out, int out_size, void* d_ws, size_t ws_size,
                              hipStream_t stream) {
    const float* x    = (const float*)d_in[0];
    const float* Wih0 = (const float*)d_in[1];
    const float* Wih  = (const float*)d_in[2];
    const float* Whh  = (const float*)d_in[3];
    const float* bih  = (const float*)d_in[4];
    const float* bhh  = (const float*)d_in[5];
    const float* fcw  = (const float*)d_in[6];
    const float* fcb  = (const float*)d_in[7];
    float* out = (float*)d_out;
    float* ws  = (float*)d_ws;

    stage_ws<<<dim3(3), dim3(1024), 0, stream>>>(Wih0, Wih, bih, bhh, fcb, ws);
    rnn_fused<<<dim3(1024), dim3(64), 0, stream>>>(x, Whh, fcw, ws, out);
    logsm<<<dim3(2048), dim3(256), 0, stream>>>(out);
}